// Round 1
// baseline (646.963 us; speedup 1.0000x reference)
//
#include <hip/hip_runtime.h>
#include <math.h>

#define BT    8192      // B*T rows
#define TSEQ  2048
#define DIN   1024
#define DK    64

// ---------------- Projection: Q/K/V = x @ Wq/Wk/Wv ----------------
// 8 rows per block staged in LDS; 64 threads; thread j owns output column j
// of all three matrices (coalesced W reads, L2-resident W).
__global__ __launch_bounds__(64) void proj_kernel(
    const float* __restrict__ x,
    const float* __restrict__ Wq, const float* __restrict__ Wk,
    const float* __restrict__ Wv,
    float* __restrict__ Q, float* __restrict__ K, float* __restrict__ V)
{
    __shared__ float4 xs[8][256];             // 8 rows x 1024 floats = 32 KB
    const int j = threadIdx.x;                // 0..63 = output column
    const int row0 = blockIdx.x * 8;

    const float4* xsrc = (const float4*)(x + (size_t)row0 * DIN);
    #pragma unroll 4
    for (int i = j; i < 8 * 256; i += 64) xs[i >> 8][i & 255] = xsrc[i];
    __syncthreads();

    float accQ[8], accK[8], accV[8];
    #pragma unroll
    for (int r = 0; r < 8; ++r) { accQ[r] = 0.f; accK[r] = 0.f; accV[r] = 0.f; }

    for (int d4 = 0; d4 < 256; ++d4) {
        const int d = d4 << 2;
        const float wq0 = Wq[(d + 0) * DK + j], wq1 = Wq[(d + 1) * DK + j];
        const float wq2 = Wq[(d + 2) * DK + j], wq3 = Wq[(d + 3) * DK + j];
        const float wk0 = Wk[(d + 0) * DK + j], wk1 = Wk[(d + 1) * DK + j];
        const float wk2 = Wk[(d + 2) * DK + j], wk3 = Wk[(d + 3) * DK + j];
        const float wv0 = Wv[(d + 0) * DK + j], wv1 = Wv[(d + 1) * DK + j];
        const float wv2 = Wv[(d + 2) * DK + j], wv3 = Wv[(d + 3) * DK + j];
        #pragma unroll
        for (int r = 0; r < 8; ++r) {
            const float4 xv = xs[r][d4];
            accQ[r] += xv.x * wq0 + xv.y * wq1 + xv.z * wq2 + xv.w * wq3;
            accK[r] += xv.x * wk0 + xv.y * wk1 + xv.z * wk2 + xv.w * wk3;
            accV[r] += xv.x * wv0 + xv.y * wv1 + xv.z * wv2 + xv.w * wv3;
        }
    }

    #pragma unroll
    for (int r = 0; r < 8; ++r) {
        const size_t o = (size_t)(row0 + r) * DK + j;
        Q[o] = accQ[r]; K[o] = accK[r]; V[o] = accV[r];
    }
}

// ---------------- Causal flash attention, one wave per query row ----------
// Lane-owns-keys: lane l processes keys s = kb*64 + l with a private online
// softmax state (m, l, o[64]); merged across lanes at the end.
__device__ inline float dot4(float4 a, float4 b) {
    return a.x * b.x + a.y * b.y + a.z * b.z + a.w * b.w;
}

__global__ __launch_bounds__(64) void attn_kernel(
    const float* __restrict__ Q, const float* __restrict__ K,
    const float* __restrict__ V, float* __restrict__ O)
{
    __shared__ float red[64][65];             // padded transpose-reduce buffer
    const int lane = threadIdx.x;
    const int r = blockIdx.x;                 // global row = b*T + t
    const int b = r >> 11;                    // T = 2048
    const int t = r & (TSEQ - 1);

    const float* Qr = Q + (size_t)r * DK;
    const float* Kb = K + (size_t)b * TSEQ * DK;
    const float* Vb = V + (size_t)b * TSEQ * DK;

    // broadcast-load full Q row into registers (same addresses in all lanes)
    float4 q[16];
    #pragma unroll
    for (int i = 0; i < 16; ++i) q[i] = ((const float4*)Qr)[i];

    const float scale = 0.125f;               // 1/sqrt(64)
    float m = -INFINITY, lsum = 0.f;
    float o[DK];
    #pragma unroll
    for (int d = 0; d < DK; ++d) o[d] = 0.f;

    const int nkb = (t >> 6) + 1;             // number of 64-key blocks
    for (int kb = 0; kb < nkb; ++kb) {
        const int s = (kb << 6) + lane;
        const bool valid = (s <= t);
        const float4* Ks = (const float4*)(Kb + (size_t)s * DK);
        float s0 = 0.f, s1 = 0.f, s2 = 0.f, s3 = 0.f;
        #pragma unroll
        for (int i = 0; i < 16; i += 4) {
            s0 += dot4(q[i + 0], Ks[i + 0]);
            s1 += dot4(q[i + 1], Ks[i + 1]);
            s2 += dot4(q[i + 2], Ks[i + 2]);
            s3 += dot4(q[i + 3], Ks[i + 3]);
        }
        float score = (s0 + s1 + s2 + s3) * scale;

        if (valid) {
            if (score > m) {
                const float f = __expf(m - score);   // exp(-inf)=0 on first hit
                lsum *= f;
                #pragma unroll
                for (int d = 0; d < DK; ++d) o[d] *= f;
                m = score;
            }
            const float p = __expf(score - m);
            lsum += p;
            const float4* Vs = (const float4*)(Vb + (size_t)s * DK);
            #pragma unroll
            for (int i = 0; i < 16; ++i) {
                const float4 v = Vs[i];
                o[4 * i + 0] += p * v.x;
                o[4 * i + 1] += p * v.y;
                o[4 * i + 2] += p * v.z;
                o[4 * i + 3] += p * v.w;
            }
        }
    }

    // ---- cross-lane merge ----
    float M = m;
    #pragma unroll
    for (int off = 32; off; off >>= 1) M = fmaxf(M, __shfl_xor(M, off));
    const float f = __expf(m - M);            // lanes with no valid key: 0
    float L = lsum * f;
    #pragma unroll
    for (int off = 32; off; off >>= 1) L += __shfl_xor(L, off);

    #pragma unroll
    for (int d = 0; d < DK; ++d) red[lane][d] = o[d] * f;
    __syncthreads();

    float sum = 0.f;
    #pragma unroll
    for (int jj = 0; jj < 64; ++jj) sum += red[jj][lane];

    O[(size_t)r * DK + lane] = sum / L;
}

extern "C" void kernel_launch(void* const* d_in, const int* in_sizes, int n_in,
                              void* d_out, int out_size, void* d_ws, size_t ws_size,
                              hipStream_t stream) {
    const float* x  = (const float*)d_in[0];
    const float* Wq = (const float*)d_in[1];
    const float* Wk = (const float*)d_in[2];
    const float* Wv = (const float*)d_in[3];
    float* O = (float*)d_out;

    float* Q = (float*)d_ws;                  // 3 x 2 MB scratch
    float* K = Q + (size_t)BT * DK;
    float* V = K + (size_t)BT * DK;

    proj_kernel<<<dim3(BT / 8), dim3(64), 0, stream>>>(x, Wq, Wk, Wv, Q, K, V);
    attn_kernel<<<dim3(BT), dim3(64), 0, stream>>>(Q, K, V, O);
}

// Round 3
// 175.764 us; speedup vs baseline: 3.6809x; 3.6809x over previous
//
#include <hip/hip_runtime.h>
#include <math.h>

#define BT    8192
#define TSEQ  2048
#define DIN   1024
#define DK    64

typedef __attribute__((ext_vector_type(8))) short bf16x8;
typedef __attribute__((ext_vector_type(4))) float f32x4;

static __device__ inline unsigned short f2bf(float f) {
    union { float f; unsigned u; } v; v.f = f;
    unsigned r = v.u + 0x7fff + ((v.u >> 16) & 1);   // RNE
    return (unsigned short)(r >> 16);
}

// ---------------- Projection: Qb = bf16(x@Wq * 0.125*log2e), Kb = bf16(x@Wk),
// ---------------- VT[b][d][t] = bf16((x@Wv)[t][d])
__global__ __launch_bounds__(256) void proj_kernel(
    const float* __restrict__ x,
    const float* __restrict__ Wq, const float* __restrict__ Wk,
    const float* __restrict__ Wv,
    unsigned short* __restrict__ Qb, unsigned short* __restrict__ Kb,
    unsigned short* __restrict__ VT)
{
    __shared__ float4 xs[8][256];                 // 8 rows x 1024 f32 = 32 KB
    const int tid = threadIdx.x;
    const int j = tid & 63;                       // output column
    const int w = tid >> 6;                       // wave id -> rows 2w, 2w+1
    const int row0 = blockIdx.x * 8;

    const float4* xsrc = (const float4*)(x + (size_t)row0 * DIN);
    #pragma unroll
    for (int i = tid; i < 2048; i += 256) xs[i >> 8][i & 255] = xsrc[i];
    __syncthreads();

    float aq0 = 0.f, aq1 = 0.f, ak0 = 0.f, ak1 = 0.f, av0 = 0.f, av1 = 0.f;
    for (int d4 = 0; d4 < 256; ++d4) {
        const int d = d4 << 2;
        float wq[4], wk[4], wv[4];
        #pragma unroll
        for (int i = 0; i < 4; ++i) {
            wq[i] = Wq[(d + i) * DK + j];
            wk[i] = Wk[(d + i) * DK + j];
            wv[i] = Wv[(d + i) * DK + j];
        }
        const float4 x0 = xs[2 * w][d4];
        const float4 x1 = xs[2 * w + 1][d4];
        aq0 += x0.x * wq[0] + x0.y * wq[1] + x0.z * wq[2] + x0.w * wq[3];
        ak0 += x0.x * wk[0] + x0.y * wk[1] + x0.z * wk[2] + x0.w * wk[3];
        av0 += x0.x * wv[0] + x0.y * wv[1] + x0.z * wv[2] + x0.w * wv[3];
        aq1 += x1.x * wq[0] + x1.y * wq[1] + x1.z * wq[2] + x1.w * wq[3];
        ak1 += x1.x * wk[0] + x1.y * wk[1] + x1.z * wk[2] + x1.w * wk[3];
        av1 += x1.x * wv[0] + x1.y * wv[1] + x1.z * wv[2] + x1.w * wv[3];
    }

    const float qsc = 0.125f * 1.44269504088896340736f;  // scale * log2(e)
    #pragma unroll
    for (int r = 0; r < 2; ++r) {
        const int t = row0 + 2 * w + r;
        const float q = r ? aq1 : aq0;
        const float k = r ? ak1 : ak0;
        const float v = r ? av1 : av0;
        Qb[(size_t)t * DK + j] = f2bf(q * qsc);
        Kb[(size_t)t * DK + j] = f2bf(k);
        const int b = t >> 11;
        VT[((size_t)b * DK + j) * TSEQ + (t & (TSEQ - 1))] = f2bf(v);
    }
}

// ---------------- MFMA flash attention: 1 wave per 16-row Q tile ------------
// S/P/O live in mfma C-layout (col = lane&15, row = (lane>>4)*4 + reg).
// Key index and causal mask use the WITHIN-BATCH row t0 = q0 & (TSEQ-1).
__global__ __launch_bounds__(64) void attn_kernel(
    const unsigned short* __restrict__ Qb, const unsigned short* __restrict__ Kb,
    const unsigned short* __restrict__ VT, float* __restrict__ O)
{
    __shared__ __align__(16) unsigned short P_lds[16][72];  // 144B row stride
    const int lane = threadIdx.x;
    // interleave batches so the 4 longest tiles launch first
    const int qt = ((blockIdx.x & 3) << 7) | (127 - (blockIdx.x >> 2));
    const int q0 = qt << 4;                       // global row
    const int t0 = q0 & (TSEQ - 1);               // within-batch row
    const int b  = q0 >> 11;
    const int lr = lane & 15;
    const int lg = lane >> 4;

    // Q A-fragments (k = 0..31, 32..63)
    const unsigned short* Qrow = Qb + (size_t)(q0 + lr) * DK + (lg << 3);
    bf16x8 qf0 = *(const bf16x8*)(Qrow);
    bf16x8 qf1 = *(const bf16x8*)(Qrow + 32);

    const unsigned short* Kbase = Kb + (size_t)b * TSEQ * DK;
    const unsigned short* Vbase = VT + (size_t)b * DK * TSEQ;

    f32x4 oacc[4];
    #pragma unroll
    for (int dt = 0; dt < 4; ++dt) oacc[dt] = (f32x4){0.f, 0.f, 0.f, 0.f};
    float m[4] = {-INFINITY, -INFINITY, -INFINITY, -INFINITY};
    float L[4] = {0.f, 0.f, 0.f, 0.f};

    const int nkb = (t0 >> 6) + 1;                // 64-key blocks, within batch
    for (int kb = 0; kb < nkb; ++kb) {
        const int s0 = kb << 6;

        // ---- S = Q K^T over 4 column tiles of 16 keys ----
        f32x4 s[4];
        #pragma unroll
        for (int ct = 0; ct < 4; ++ct) {
            const unsigned short* Krow =
                Kbase + (size_t)(s0 + ct * 16 + lr) * DK + (lg << 3);
            bf16x8 k0 = *(const bf16x8*)(Krow);
            bf16x8 k1 = *(const bf16x8*)(Krow + 32);
            f32x4 acc = (f32x4){0.f, 0.f, 0.f, 0.f};
            acc = __builtin_amdgcn_mfma_f32_16x16x32_bf16(qf0, k0, acc, 0, 0, 0);
            acc = __builtin_amdgcn_mfma_f32_16x16x32_bf16(qf1, k1, acc, 0, 0, 0);
            s[ct] = acc;
        }

        // ---- causal mask (only the diagonal block needs it) ----
        if (kb == nkb - 1) {
            #pragma unroll
            for (int ct = 0; ct < 4; ++ct)
                #pragma unroll
                for (int r = 0; r < 4; ++r)
                    if (s0 + ct * 16 + lr > t0 + lg * 4 + r) s[ct][r] = -INFINITY;
        }

        // ---- online softmax (S already in log2 units) ----
        float tmax[4];
        #pragma unroll
        for (int r = 0; r < 4; ++r)
            tmax[r] = fmaxf(fmaxf(s[0][r], s[1][r]), fmaxf(s[2][r], s[3][r]));
        #pragma unroll
        for (int off = 1; off < 16; off <<= 1)
            #pragma unroll
            for (int r = 0; r < 4; ++r)
                tmax[r] = fmaxf(tmax[r], __shfl_xor(tmax[r], off));

        float f[4];
        #pragma unroll
        for (int r = 0; r < 4; ++r) {
            const float mn = fmaxf(m[r], tmax[r]);
            f[r] = exp2f(m[r] - mn);
            m[r] = mn;
        }

        float ps[4] = {0.f, 0.f, 0.f, 0.f};
        unsigned short pb[4][4];
        #pragma unroll
        for (int ct = 0; ct < 4; ++ct)
            #pragma unroll
            for (int r = 0; r < 4; ++r) {
                const float p = exp2f(s[ct][r] - m[r]);
                ps[r] += p;
                pb[ct][r] = f2bf(p);
            }
        #pragma unroll
        for (int r = 0; r < 4; ++r) L[r] = L[r] * f[r] + ps[r];
        #pragma unroll
        for (int r = 0; r < 4; ++r) {
            oacc[0][r] *= f[r]; oacc[1][r] *= f[r];
            oacc[2][r] *= f[r]; oacc[3][r] *= f[r];
        }

        // ---- P: C-layout regs -> LDS -> A-fragments ----
        #pragma unroll
        for (int ct = 0; ct < 4; ++ct)
            #pragma unroll
            for (int r = 0; r < 4; ++r)
                P_lds[lg * 4 + r][ct * 16 + lr] = pb[ct][r];
        __syncthreads();
        bf16x8 pf0 = *(const bf16x8*)&P_lds[lr][(lg << 3)];
        bf16x8 pf1 = *(const bf16x8*)&P_lds[lr][32 + (lg << 3)];
        __syncthreads();

        // ---- O += P V over 4 output-column tiles ----
        #pragma unroll
        for (int dt = 0; dt < 4; ++dt) {
            const unsigned short* Vrow =
                Vbase + (size_t)(dt * 16 + lr) * TSEQ + s0 + (lg << 3);
            bf16x8 v0 = *(const bf16x8*)(Vrow);
            bf16x8 v1 = *(const bf16x8*)(Vrow + 32);
            oacc[dt] = __builtin_amdgcn_mfma_f32_16x16x32_bf16(pf0, v0, oacc[dt], 0, 0, 0);
            oacc[dt] = __builtin_amdgcn_mfma_f32_16x16x32_bf16(pf1, v1, oacc[dt], 0, 0, 0);
        }
    }

    // ---- final: reduce L across the 16-lane col groups, normalize, store ----
    #pragma unroll
    for (int off = 1; off < 16; off <<= 1)
        #pragma unroll
        for (int r = 0; r < 4; ++r) L[r] += __shfl_xor(L[r], off);

    #pragma unroll
    for (int r = 0; r < 4; ++r) {
        const float inv = 1.0f / L[r];
        const size_t row = (size_t)(q0 + lg * 4 + r) * DK;
        #pragma unroll
        for (int dt = 0; dt < 4; ++dt)
            O[row + dt * 16 + lr] = oacc[dt][r] * inv;
    }
}

extern "C" void kernel_launch(void* const* d_in, const int* in_sizes, int n_in,
                              void* d_out, int out_size, void* d_ws, size_t ws_size,
                              hipStream_t stream) {
    const float* x  = (const float*)d_in[0];
    const float* Wq = (const float*)d_in[1];
    const float* Wk = (const float*)d_in[2];
    const float* Wv = (const float*)d_in[3];
    float* O = (float*)d_out;

    unsigned short* Qb = (unsigned short*)d_ws;                 // 1 MB
    unsigned short* Kb = Qb + (size_t)BT * DK;                  // 1 MB
    unsigned short* VT = Kb + (size_t)BT * DK;                  // 1 MB

    proj_kernel<<<dim3(BT / 8), dim3(256), 0, stream>>>(x, Wq, Wk, Wv, Qb, Kb, VT);
    attn_kernel<<<dim3(512), dim3(64), 0, stream>>>(Qb, Kb, VT, O);
}

// Round 4
// 69.153 us; speedup vs baseline: 9.3555x; 2.5417x over previous
//
#include <hip/hip_runtime.h>
#include <math.h>

#define BT    8192
#define TSEQ  2048
#define DIN   1024
#define DK    64

typedef __attribute__((ext_vector_type(8))) short bf16x8;
typedef __attribute__((ext_vector_type(4))) float f32x4;

static __device__ inline unsigned short f2bf(float f) {
    union { float f; unsigned u; } v; v.f = f;
    unsigned r = v.u + 0x7fff + ((v.u >> 16) & 1);   // RNE
    return (unsigned short)(r >> 16);
}

static __device__ inline bf16x8 cvt8(float4 a, float4 b) {
    bf16x8 r;
    r[0] = (short)f2bf(a.x); r[1] = (short)f2bf(a.y);
    r[2] = (short)f2bf(a.z); r[3] = (short)f2bf(a.w);
    r[4] = (short)f2bf(b.x); r[5] = (short)f2bf(b.y);
    r[6] = (short)f2bf(b.z); r[7] = (short)f2bf(b.w);
    return r;
}

// ---------------- WT[mat*64+n][k] = bf16(W[k][n]) : [192][1024] -------------
__global__ __launch_bounds__(256) void wt_kernel(
    const float* __restrict__ Wq, const float* __restrict__ Wk,
    const float* __restrict__ Wv, unsigned short* __restrict__ WT)
{
    __shared__ float ws[64][65];
    const int tid = threadIdx.x;
    const int mat = blockIdx.x >> 4;               // 0..2
    const int k0  = (blockIdx.x & 15) << 6;        // 0..960
    const float* W = (mat == 0) ? Wq : ((mat == 1) ? Wk : Wv);

    const int j = tid & 63;
    for (int i = tid >> 6; i < 64; i += 4)
        ws[i][j] = W[(size_t)(k0 + i) * DK + j];
    __syncthreads();

    const int n  = tid & 63;
    const int c0 = (tid >> 6) << 4;
    unsigned short* dst = WT + (size_t)(mat * 64 + n) * DIN + k0 + c0;
    #pragma unroll
    for (int c = 0; c < 16; ++c) dst[c] = f2bf(ws[c0 + c][n]);
}

// ---------------- MFMA projection: block = 2 rowgroups x 2 colgroups --------
// Wave (rowg,colg): 16 rows x 96 cols. A-frags straight from fp32 x (cvt in
// reg), B-frags from bf16 WT (k-contiguous 16B). No LDS.
__global__ __launch_bounds__(256) void proj_kernel(
    const float* __restrict__ x, const unsigned short* __restrict__ WT,
    unsigned short* __restrict__ Qb, unsigned short* __restrict__ Kb,
    unsigned short* __restrict__ VT)
{
    const int lane = threadIdx.x & 63;
    const int w    = threadIdx.x >> 6;
    const int lr = lane & 15, lg = lane >> 4;
    const int rowg = w >> 1, colg = w & 1;
    const int m0 = blockIdx.x * 32 + rowg * 16;

    const float* xrow = x + (size_t)(m0 + lr) * DIN + (lg << 3);
    const unsigned short* wbase = WT + (size_t)(colg * 96 + lr) * DIN + (lg << 3);

    f32x4 acc[6];
    #pragma unroll
    for (int nt = 0; nt < 6; ++nt) acc[nt] = (f32x4){0.f, 0.f, 0.f, 0.f};

    #pragma unroll 2
    for (int k0 = 0; k0 < DIN; k0 += 32) {
        const float4 a0 = *(const float4*)(xrow + k0);
        const float4 a1 = *(const float4*)(xrow + k0 + 4);
        const bf16x8 af = cvt8(a0, a1);
        #pragma unroll
        for (int nt = 0; nt < 6; ++nt) {
            const bf16x8 bf = *(const bf16x8*)(wbase + (size_t)nt * 16 * DIN + k0);
            acc[nt] = __builtin_amdgcn_mfma_f32_16x16x32_bf16(af, bf, acc[nt], 0, 0, 0);
        }
    }

    const float qsc = 0.125f * 1.44269504088896340736f;  // scale * log2(e)
    #pragma unroll
    for (int nt = 0; nt < 6; ++nt) {
        const int gct = colg * 6 + nt;                   // global 16-col tile
        #pragma unroll
        for (int r = 0; r < 4; ++r) {
            const int row = m0 + (lg << 2) + r;
            const float vv = acc[nt][r];
            if (gct < 4) {
                Qb[(size_t)row * DK + gct * 16 + lr] = f2bf(vv * qsc);
            } else if (gct < 8) {
                Kb[(size_t)row * DK + (gct - 4) * 16 + lr] = f2bf(vv);
            } else {
                const int d = (gct - 8) * 16 + lr;
                VT[((size_t)(row >> 11) * DK + d) * TSEQ + (row & (TSEQ - 1))] = f2bf(vv);
            }
        }
    }
}

// ---------------- MFMA flash attention, 4-way split-K per Q-tile ------------
// Wave w handles key-blocks kb ≡ w (mod 4) with private online softmax;
// flash-merge across waves at the end. No block barrier inside the loop.
__global__ __launch_bounds__(256) void attn_kernel(
    const unsigned short* __restrict__ Qb, const unsigned short* __restrict__ Kb,
    const unsigned short* __restrict__ VT, float* __restrict__ O)
{
    __shared__ __align__(16) unsigned short P_lds[4][16][72];
    __shared__ float Opart[4][16][68];
    __shared__ float mpart[4][16];
    __shared__ float Lpart[4][16];

    const int lane = threadIdx.x & 63;
    const int w    = threadIdx.x >> 6;
    // interleave batches so the 4 longest tiles launch first
    const int qt = ((blockIdx.x & 3) << 7) | (127 - (blockIdx.x >> 2));
    const int q0 = qt << 4;                       // global row
    const int t0 = q0 & (TSEQ - 1);               // within-batch row
    const int b  = q0 >> 11;
    const int lr = lane & 15;
    const int lg = lane >> 4;

    const unsigned short* Qrow = Qb + (size_t)(q0 + lr) * DK + (lg << 3);
    const bf16x8 qf0 = *(const bf16x8*)(Qrow);
    const bf16x8 qf1 = *(const bf16x8*)(Qrow + 32);

    const unsigned short* Kbase = Kb + (size_t)b * TSEQ * DK;
    const unsigned short* Vbase = VT + (size_t)b * DK * TSEQ;

    f32x4 oacc[4];
    #pragma unroll
    for (int dt = 0; dt < 4; ++dt) oacc[dt] = (f32x4){0.f, 0.f, 0.f, 0.f};
    float m[4] = {-INFINITY, -INFINITY, -INFINITY, -INFINITY};
    float L[4] = {0.f, 0.f, 0.f, 0.f};

    const int nkb = (t0 >> 6) + 1;                // 64-key blocks, within batch
    for (int kb = w; kb < nkb; kb += 4) {
        const int s0 = kb << 6;

        // ---- S = Q K^T over 4 column tiles of 16 keys ----
        f32x4 s[4];
        #pragma unroll
        for (int ct = 0; ct < 4; ++ct) {
            const unsigned short* Krow =
                Kbase + (size_t)(s0 + ct * 16 + lr) * DK + (lg << 3);
            const bf16x8 k0 = *(const bf16x8*)(Krow);
            const bf16x8 k1 = *(const bf16x8*)(Krow + 32);
            f32x4 a = (f32x4){0.f, 0.f, 0.f, 0.f};
            a = __builtin_amdgcn_mfma_f32_16x16x32_bf16(qf0, k0, a, 0, 0, 0);
            a = __builtin_amdgcn_mfma_f32_16x16x32_bf16(qf1, k1, a, 0, 0, 0);
            s[ct] = a;
        }

        // ---- causal mask (only the diagonal block) ----
        if (kb == nkb - 1) {
            #pragma unroll
            for (int ct = 0; ct < 4; ++ct)
                #pragma unroll
                for (int r = 0; r < 4; ++r)
                    if (s0 + ct * 16 + lr > t0 + lg * 4 + r) s[ct][r] = -INFINITY;
        }

        // ---- online softmax (log2 domain) ----
        float tmax[4];
        #pragma unroll
        for (int r = 0; r < 4; ++r)
            tmax[r] = fmaxf(fmaxf(s[0][r], s[1][r]), fmaxf(s[2][r], s[3][r]));
        #pragma unroll
        for (int off = 1; off < 16; off <<= 1)
            #pragma unroll
            for (int r = 0; r < 4; ++r)
                tmax[r] = fmaxf(tmax[r], __shfl_xor(tmax[r], off));

        float f[4];
        #pragma unroll
        for (int r = 0; r < 4; ++r) {
            const float mn = fmaxf(m[r], tmax[r]);
            f[r] = exp2f(m[r] - mn);
            m[r] = mn;
        }

        float ps[4] = {0.f, 0.f, 0.f, 0.f};
        unsigned short pb[4][4];
        #pragma unroll
        for (int ct = 0; ct < 4; ++ct)
            #pragma unroll
            for (int r = 0; r < 4; ++r) {
                const float p = exp2f(s[ct][r] - m[r]);
                ps[r] += p;
                pb[ct][r] = f2bf(p);
            }
        #pragma unroll
        for (int r = 0; r < 4; ++r) L[r] = L[r] * f[r] + ps[r];
        #pragma unroll
        for (int r = 0; r < 4; ++r) {
            oacc[0][r] *= f[r]; oacc[1][r] *= f[r];
            oacc[2][r] *= f[r]; oacc[3][r] *= f[r];
        }

        // ---- P: C-layout regs -> per-wave LDS -> A-fragments ----
        #pragma unroll
        for (int ct = 0; ct < 4; ++ct)
            #pragma unroll
            for (int r = 0; r < 4; ++r)
                P_lds[w][lg * 4 + r][ct * 16 + lr] = pb[ct][r];
        asm volatile("s_waitcnt lgkmcnt(0)" ::: "memory");
        const bf16x8 pf0 = *(const bf16x8*)&P_lds[w][lr][(lg << 3)];
        const bf16x8 pf1 = *(const bf16x8*)&P_lds[w][lr][32 + (lg << 3)];

        // ---- O += P V ----
        #pragma unroll
        for (int dt = 0; dt < 4; ++dt) {
            const unsigned short* Vrow =
                Vbase + (size_t)(dt * 16 + lr) * TSEQ + s0 + (lg << 3);
            const bf16x8 v0 = *(const bf16x8*)(Vrow);
            const bf16x8 v1 = *(const bf16x8*)(Vrow + 32);
            oacc[dt] = __builtin_amdgcn_mfma_f32_16x16x32_bf16(pf0, v0, oacc[dt], 0, 0, 0);
            oacc[dt] = __builtin_amdgcn_mfma_f32_16x16x32_bf16(pf1, v1, oacc[dt], 0, 0, 0);
        }
    }

    // ---- per-wave finish: reduce L across lr-groups, store partials ----
    #pragma unroll
    for (int off = 1; off < 16; off <<= 1)
        #pragma unroll
        for (int r = 0; r < 4; ++r) L[r] += __shfl_xor(L[r], off);

    #pragma unroll
    for (int dt = 0; dt < 4; ++dt)
        #pragma unroll
        for (int r = 0; r < 4; ++r)
            Opart[w][(lg << 2) + r][dt * 16 + lr] = oacc[dt][r];
    if (lr == 0) {
        #pragma unroll
        for (int r = 0; r < 4; ++r) {
            mpart[w][(lg << 2) + r] = m[r];
            Lpart[w][(lg << 2) + r] = L[r];
        }
    }
    __syncthreads();

    // ---- flash-merge; wave w writes output col-tile w ----
    #pragma unroll
    for (int r = 0; r < 4; ++r) {
        const int row = (lg << 2) + r;
        const float M = fmaxf(fmaxf(mpart[0][row], mpart[1][row]),
                              fmaxf(mpart[2][row], mpart[3][row]));
        float Lf = 0.f, o = 0.f;
        #pragma unroll
        for (int v = 0; v < 4; ++v) {
            const float fv = exp2f(mpart[v][row] - M);
            Lf += fv * Lpart[v][row];
            o  += fv * Opart[v][row][(w << 4) + lr];
        }
        O[(size_t)(q0 + row) * DK + (w << 4) + lr] = o / Lf;
    }
}

extern "C" void kernel_launch(void* const* d_in, const int* in_sizes, int n_in,
                              void* d_out, int out_size, void* d_ws, size_t ws_size,
                              hipStream_t stream) {
    const float* x  = (const float*)d_in[0];
    const float* Wq = (const float*)d_in[1];
    const float* Wk = (const float*)d_in[2];
    const float* Wv = (const float*)d_in[3];
    float* O = (float*)d_out;

    unsigned short* Qb = (unsigned short*)d_ws;                 // 1 MB
    unsigned short* Kb = Qb + (size_t)BT * DK;                  // 1 MB
    unsigned short* VT = Kb + (size_t)BT * DK;                  // 1 MB
    unsigned short* WT = VT + (size_t)BT * DK;                  // 384 KB

    wt_kernel  <<<dim3(48),  dim3(256), 0, stream>>>(Wq, Wk, Wv, WT);
    proj_kernel<<<dim3(256), dim3(256), 0, stream>>>(x, WT, Qb, Kb, VT);
    attn_kernel<<<dim3(512), dim3(256), 0, stream>>>(Qb, Kb, VT, O);
}